// Round 1
// baseline (1840.150 us; speedup 1.0000x reference)
//
#include <hip/hip_runtime.h>
#include <hip/hip_bf16.h>
#include <math.h>

#define NPTS   30000
#define CIN    128
#define COUT   256
#define KNBR   16
#define PPB    4      // points per block, one wave (64 lanes) each

// Each wave owns one point. Lane owns 4 output channels d = r*64 + lane.
// LDS per wave: 8 edge rows of 256 f32 (reused for h), + center row.
__global__ __launch_bounds__(256, 4) void edgeconv_fused_f32(
    const float* __restrict__ feat,
    const int*   __restrict__ knn,
    const float* __restrict__ W1, const float* __restrict__ b1,
    const float* __restrict__ W2, const float* __restrict__ b2,
    const float* __restrict__ Ws, const float* __restrict__ bs,
    const float* __restrict__ gamma, const float* __restrict__ beta,
    float* __restrict__ out)
{
    __shared__ float s_buf[PPB][8][COUT];   // edge rows, then overwritten by h
    __shared__ float s_cen[PPB][CIN];

    const int wave = threadIdx.x >> 6;
    const int lane = threadIdx.x & 63;
    const int n    = blockIdx.x * PPB + wave;   // 30000 % 4 == 0 -> always valid

    float (*buf)[COUT] = s_buf[wave];
    float *cen = s_cen[wave];

    // ---- center row into LDS (2 floats per lane) ----
    {
        float2 c2 = *(const float2*)&feat[n * CIN + lane * 2];
        *(float2*)&cen[lane * 2] = c2;
    }

    // ---- biases for this lane's 4 channels ----
    float b1v[4], b2v[4];
    #pragma unroll
    for (int r = 0; r < 4; ++r) {
        b1v[r] = b1[r * 64 + lane];
        b2v[r] = b2[r * 64 + lane];
    }

    float mx[4];
    #pragma unroll
    for (int r = 0; r < 4; ++r) mx[r] = -INFINITY;

    #pragma unroll 1
    for (int half = 0; half < 2; ++half) {
        // ---- build 8 edge rows: [center(128) | nbr-center(128)] ----
        #pragma unroll
        for (int kk = 0; kk < 8; ++kk) {
            int idx = knn[n * KNBR + half * 8 + kk];
            float2 nb = *(const float2*)&feat[idx * CIN + lane * 2];
            float2 c2 = *(const float2*)&cen[lane * 2];
            *(float2*)&buf[kk][lane * 2] = c2;
            float2 df; df.x = nb.x - c2.x; df.y = nb.y - c2.y;
            *(float2*)&buf[kk][CIN + lane * 2] = df;
        }

        // ---- GEMM1: h[kk][d] = gelu(edge[kk][:] . W1[:,d] + b1[d]) ----
        float acc[8][4];
        #pragma unroll
        for (int kk = 0; kk < 8; ++kk) {
            #pragma unroll
            for (int r = 0; r < 4; ++r) acc[kk][r] = b1v[r];
        }

        #pragma unroll 2
        for (int c = 0; c < COUT; c += 4) {
            float w0[4], w1[4], w2[4], w3[4];
            #pragma unroll
            for (int r = 0; r < 4; ++r) {
                const float* wp = &W1[c * COUT + r * 64 + lane];
                w0[r] = wp[0];
                w1[r] = wp[COUT];
                w2[r] = wp[2 * COUT];
                w3[r] = wp[3 * COUT];
            }
            #pragma unroll
            for (int kk = 0; kk < 8; ++kk) {
                float4 e = *(const float4*)&buf[kk][c];   // uniform -> LDS broadcast
                #pragma unroll
                for (int r = 0; r < 4; ++r)
                    acc[kk][r] = fmaf(e.w, w3[r],
                                  fmaf(e.z, w2[r],
                                   fmaf(e.y, w1[r],
                                    fmaf(e.x, w0[r], acc[kk][r]))));
            }
        }

        // ---- exact GELU, store h over edge buffer ----
        #pragma unroll
        for (int kk = 0; kk < 8; ++kk) {
            #pragma unroll
            for (int r = 0; r < 4; ++r) {
                float x = acc[kk][r];
                float g = 0.5f * x * (1.0f + erff(x * 0.70710678118654752f));
                buf[kk][r * 64 + lane] = g;
            }
        }

        // ---- GEMM2: eo[kk][e] = h[kk][:] . W2[:,e] + b2[e]; max into mx ----
        float acc2[8][4];
        #pragma unroll
        for (int kk = 0; kk < 8; ++kk) {
            #pragma unroll
            for (int r = 0; r < 4; ++r) acc2[kk][r] = b2v[r];
        }

        #pragma unroll 2
        for (int c = 0; c < COUT; c += 4) {
            float w0[4], w1[4], w2[4], w3[4];
            #pragma unroll
            for (int r = 0; r < 4; ++r) {
                const float* wp = &W2[c * COUT + r * 64 + lane];
                w0[r] = wp[0];
                w1[r] = wp[COUT];
                w2[r] = wp[2 * COUT];
                w3[r] = wp[3 * COUT];
            }
            #pragma unroll
            for (int kk = 0; kk < 8; ++kk) {
                float4 h4 = *(const float4*)&buf[kk][c];
                #pragma unroll
                for (int r = 0; r < 4; ++r)
                    acc2[kk][r] = fmaf(h4.w, w3[r],
                                   fmaf(h4.z, w2[r],
                                    fmaf(h4.y, w1[r],
                                     fmaf(h4.x, w0[r], acc2[kk][r]))));
            }
        }

        #pragma unroll
        for (int kk = 0; kk < 8; ++kk) {
            #pragma unroll
            for (int r = 0; r < 4; ++r)
                mx[r] = fmaxf(mx[r], acc2[kk][r]);
        }
    }

    // ---- skip: feat[n] @ Ws + bs ----
    float sk[4];
    #pragma unroll
    for (int r = 0; r < 4; ++r) sk[r] = bs[r * 64 + lane];

    #pragma unroll 2
    for (int c = 0; c < CIN; c += 4) {
        float w0[4], w1[4], w2[4], w3[4];
        #pragma unroll
        for (int r = 0; r < 4; ++r) {
            const float* wp = &Ws[c * COUT + r * 64 + lane];
            w0[r] = wp[0];
            w1[r] = wp[COUT];
            w2[r] = wp[2 * COUT];
            w3[r] = wp[3 * COUT];
        }
        float4 c4 = *(const float4*)&cen[c];
        #pragma unroll
        for (int r = 0; r < 4; ++r)
            sk[r] = fmaf(c4.w, w3[r],
                     fmaf(c4.z, w2[r],
                      fmaf(c4.y, w1[r],
                       fmaf(c4.x, w0[r], sk[r]))));
    }

    // ---- x = max + skip; LayerNorm over 256 channels (wave allreduce) ----
    float x[4];
    #pragma unroll
    for (int r = 0; r < 4; ++r) x[r] = mx[r] + sk[r];

    float s  = x[0] + x[1] + x[2] + x[3];
    float ss = x[0]*x[0] + x[1]*x[1] + x[2]*x[2] + x[3]*x[3];
    #pragma unroll
    for (int off = 1; off < 64; off <<= 1) {
        s  += __shfl_xor(s,  off);
        ss += __shfl_xor(ss, off);
    }
    const float mu  = s * (1.0f / 256.0f);
    const float var = ss * (1.0f / 256.0f) - mu * mu;
    const float rstd = rsqrtf(var + 1e-5f);

    #pragma unroll
    for (int r = 0; r < 4; ++r) {
        int e = r * 64 + lane;
        out[n * COUT + e] = (x[r] - mu) * rstd * gamma[e] + beta[e];
    }
}

extern "C" void kernel_launch(void* const* d_in, const int* in_sizes, int n_in,
                              void* d_out, int out_size, void* d_ws, size_t ws_size,
                              hipStream_t stream) {
    const float* feat  = (const float*)d_in[0];
    const int*   knn   = (const int*)  d_in[1];
    const float* W1    = (const float*)d_in[2];
    const float* b1    = (const float*)d_in[3];
    const float* W2    = (const float*)d_in[4];
    const float* b2    = (const float*)d_in[5];
    const float* Ws    = (const float*)d_in[6];
    const float* bs    = (const float*)d_in[7];
    const float* gamma = (const float*)d_in[8];
    const float* beta  = (const float*)d_in[9];
    float* out = (float*)d_out;

    dim3 grid(NPTS / PPB);   // 7500 blocks, 4 points each
    dim3 block(256);
    hipLaunchKernelGGL(edgeconv_fused_f32, grid, block, 0, stream,
                       feat, knn, W1, b1, W2, b2, Ws, bs, gamma, beta, out);
}

// Round 2
// 409.496 us; speedup vs baseline: 4.4937x; 4.4937x over previous
//
#include <hip/hip_runtime.h>
#include <hip/hip_bf16.h>
#include <math.h>

#define NPTS   30000
#define CIN    128
#define COUT   256
#define KNN    16
#define BP     8               // points per batch iteration
#define ROWS   (BP*KNN)        // 128 edge rows per batch
#define NBATCH (NPTS/BP)       // 3750
#define GRID   256

typedef __attribute__((ext_vector_type(8)))  __bf16 bf16x8;
typedef __attribute__((ext_vector_type(16))) float  f32x16;

__device__ inline unsigned short f2bf(float x) {
    unsigned u = __builtin_bit_cast(unsigned, x);
    return (unsigned short)((u + 0x7FFFu + ((u >> 16) & 1u)) >> 16);   // RNE
}

// tanh-form GELU: |gelu_tanh - gelu_erf| ~1e-3, subdominant to bf16 h quantization
__device__ inline float gelu(float x) {
    float x3 = x * x * x;
    float u2 = 1.5957691216057308f * (x + 0.044715f * x3);  // 2*sqrt(2/pi)*(x+...)
    float e  = __expf(u2);
    float th = 1.0f - 2.0f / (e + 1.0f);                    // tanh(u2/2)
    return 0.5f * x * (1.0f + th);
}

// byte offset into a 512B-stride row-major LDS tile, XOR-swizzled (T2)
__device__ inline unsigned sw512(unsigned row, unsigned byteInRow) {
    return row * 512u + (byteInRow ^ ((row & 7u) << 4));
}
// 256B-stride variant (center-feature tile)
__device__ inline unsigned sw256(unsigned row, unsigned byteInRow) {
    return row * 256u + (byteInRow ^ ((row & 7u) << 4));
}

// ---- prep: transpose weights to bf16 [outch][inch] row-major in ws ----
__global__ void prep_w(const float* __restrict__ W1, const float* __restrict__ W2,
                       const float* __restrict__ Ws,
                       unsigned short* __restrict__ w1t, unsigned short* __restrict__ w2t,
                       unsigned short* __restrict__ wst) {
    int tid = blockIdx.x * 256 + threadIdx.x;
    if (tid < 65536) {                 // W1T, W2T: [256][256], w?t[d*256+c] = W?[c*256+d]
        int d = tid >> 8, c = tid & 255;
        w1t[tid] = f2bf(W1[c * 256 + d]);
        w2t[tid] = f2bf(W2[c * 256 + d]);
    }
    if (tid < 32768) {                 // WsT: [256][128], wst[e*128+c] = Ws[c*256+e]
        int e = tid >> 7, c = tid & 127;
        wst[tid] = f2bf(Ws[c * 256 + e]);
    }
}

__global__ __launch_bounds__(512) void edgeconv_mfma(
    const float* __restrict__ feat, const int* __restrict__ knn,
    const unsigned short* __restrict__ w1t, const unsigned short* __restrict__ w2t,
    const unsigned short* __restrict__ wst,
    const float* __restrict__ b1, const float* __restrict__ b2,
    const float* __restrict__ bs,
    const float* __restrict__ gamma, const float* __restrict__ beta,
    float* __restrict__ out)
{
    __shared__ __align__(16) unsigned char s_edge[ROWS * 512];  // 64 KB edge rows, bf16, swizzled
    __shared__ __align__(16) unsigned char s_h   [ROWS * 512];  // 64 KB h rows, bf16, swizzled
    __shared__ __align__(16) unsigned char s_fc  [32 * 256];    // 8 KB center rows, bf16, swizzled
    __shared__ float s_agg[BP][264];                            // padded stride vs bank conflicts

    const int lane = threadIdx.x & 63;
    const int wv   = threadIdx.x >> 6;      // 0..7
    const int l31  = lane & 31;
    const int lh   = lane >> 5;             // 0/1
    const int dbase = wv * 32;              // this wave's 32 output channels (both GEMMs)

    // ---- persistent A-fragments: W1T/W2T rows [dbase..dbase+31], all K ----
    // A-frag (32x32x16): lane l -> A[l&31][(l>>5)*8 + j], 8 contiguous bf16 = 16B
    bf16x8 w1a[16], w2a[16];
    {
        const unsigned short* p1 = w1t + (dbase + l31) * 256 + lh * 8;
        const unsigned short* p2 = w2t + (dbase + l31) * 256 + lh * 8;
        #pragma unroll
        for (int ks = 0; ks < 16; ++ks) {
            w1a[ks] = *(const bf16x8*)(p1 + ks * 16);
            w2a[ks] = *(const bf16x8*)(p2 + ks * 16);
        }
    }
    // bias regs: value r <-> channel dbase + (r&3) + 8*(r>>2) + 4*lh  (C/D row map)
    float b1v[16], b2bs[16];
    #pragma unroll
    for (int r = 0; r < 16; ++r) {
        int ch = dbase + (r & 3) + 8 * (r >> 2) + 4 * lh;
        b1v[r]  = b1[ch];
        b2bs[r] = b2[ch] + bs[ch];
    }

    for (int bat = blockIdx.x; bat < NBATCH; bat += GRID) {
        const int p0 = bat * BP;

        // ================= stage: wave wv gathers point p0+wv =================
        {
            const int n = p0 + wv;
            int idxs[KNN];
            #pragma unroll
            for (int kk = 0; kk < KNN; ++kk) idxs[kk] = knn[n * KNN + kk];

            const float2 c2 = *(const float2*)&feat[n * CIN + lane * 2];
            const unsigned cpk = (unsigned)f2bf(c2.x) | ((unsigned)f2bf(c2.y) << 16);
            *(unsigned*)(s_fc + sw256((unsigned)wv, (unsigned)(lane * 4))) = cpk;

            #pragma unroll
            for (int kk = 0; kk < KNN; ++kk) {
                float2 nb = *(const float2*)&feat[(long)idxs[kk] * CIN + lane * 2];
                unsigned row = (unsigned)(wv * KNN + kk);
                unsigned dpk = (unsigned)f2bf(nb.x - c2.x) | ((unsigned)f2bf(nb.y - c2.y) << 16);
                *(unsigned*)(s_edge + sw512(row, (unsigned)(lane * 4)))       = cpk;  // center half
                *(unsigned*)(s_edge + sw512(row, (unsigned)(256 + lane * 4))) = dpk;  // diff half
            }
        }
        __syncthreads();

        // ================= GEMM1: h^T = W1T . edge^T, +b1, GELU, -> s_h =================
        #pragma unroll 1
        for (int nt = 0; nt < 4; ++nt) {
            f32x16 acc = (f32x16)0.0f;
            const unsigned row  = (unsigned)(nt * 32 + l31);   // edge row (D col)
            const unsigned rb   = row * 512u;
            const unsigned swz  = (row & 7u) << 4;
            #pragma unroll
            for (int ks = 0; ks < 16; ++ks) {
                unsigned b = (unsigned)(ks * 32 + lh * 16);
                bf16x8 bf = *(const bf16x8*)(s_edge + (rb + (b ^ swz)));
                acc = __builtin_amdgcn_mfma_f32_32x32x16_bf16(w1a[ks], bf, acc, 0, 0, 0);
            }
            // epilogue: bias + gelu, pack 4 consecutive channels -> b64 write
            #pragma unroll
            for (int g = 0; g < 4; ++g) {
                float v0 = gelu(acc[4*g+0] + b1v[4*g+0]);
                float v1 = gelu(acc[4*g+1] + b1v[4*g+1]);
                float v2 = gelu(acc[4*g+2] + b1v[4*g+2]);
                float v3 = gelu(acc[4*g+3] + b1v[4*g+3]);
                uint2 val;
                val.x = (unsigned)f2bf(v0) | ((unsigned)f2bf(v1) << 16);
                val.y = (unsigned)f2bf(v2) | ((unsigned)f2bf(v3) << 16);
                int d0 = dbase + 8 * g + 4 * lh;               // 4 consecutive channels
                *(uint2*)(s_h + (rb + (((unsigned)(d0 * 2)) ^ swz))) = val;
            }
        }
        __syncthreads();

        // ================= GEMM2: eo^T = W2T . h^T, max over 16 edge rows =================
        #pragma unroll 1
        for (int nt = 0; nt < 4; ++nt) {
            f32x16 acc = (f32x16)0.0f;
            const unsigned row = (unsigned)(nt * 32 + l31);
            const unsigned rb  = row * 512u;
            const unsigned swz = (row & 7u) << 4;
            #pragma unroll
            for (int ks = 0; ks < 16; ++ks) {
                unsigned b = (unsigned)(ks * 32 + lh * 16);
                bf16x8 bf = *(const bf16x8*)(s_h + (rb + (b ^ swz)));
                acc = __builtin_amdgcn_mfma_f32_32x32x16_bf16(w2a[ks], bf, acc, 0, 0, 0);
            }
            // max over the 16 rows of each point: lanes xor {1,2,4,8} within 16-lane groups
            #pragma unroll
            for (int r = 0; r < 16; ++r) {
                float v = acc[r];
                v = fmaxf(v, __shfl_xor(v, 1));
                v = fmaxf(v, __shfl_xor(v, 2));
                v = fmaxf(v, __shfl_xor(v, 4));
                v = fmaxf(v, __shfl_xor(v, 8));
                acc[r] = v;
            }
            // lane selects reg (lane&15) via static cndmask tree (rule #20: no runtime idx)
            const int rsel = lane & 15;
            float s0 = (rsel & 1) ? acc[1]  : acc[0];
            float s1 = (rsel & 1) ? acc[3]  : acc[2];
            float s2 = (rsel & 1) ? acc[5]  : acc[4];
            float s3 = (rsel & 1) ? acc[7]  : acc[6];
            float s4 = (rsel & 1) ? acc[9]  : acc[8];
            float s5 = (rsel & 1) ? acc[11] : acc[10];
            float s6 = (rsel & 1) ? acc[13] : acc[12];
            float s7 = (rsel & 1) ? acc[15] : acc[14];
            float t0 = (rsel & 2) ? s1 : s0;
            float t1 = (rsel & 2) ? s3 : s2;
            float t2 = (rsel & 2) ? s5 : s4;
            float t3 = (rsel & 2) ? s7 : s6;
            float u0 = (rsel & 4) ? t1 : t0;
            float u1 = (rsel & 4) ? t3 : t2;
            float val = (rsel & 8) ? u1 : u0;
            int e = dbase + (rsel & 3) + 8 * (rsel >> 2) + 4 * lh;
            int p = nt * 2 + ((lane >> 4) & 1);
            s_agg[p][e] = val;
        }

        // ================= skip: Ws^T . feat_c^T (8 MFMA), add into agg =================
        {
            f32x16 acs = (f32x16)0.0f;
            const unsigned short* ps = wst + (dbase + l31) * 128 + lh * 8;
            const unsigned frow = (unsigned)l31;
            #pragma unroll
            for (int ks = 0; ks < 8; ++ks) {
                bf16x8 wf = *(const bf16x8*)(ps + ks * 16);
                bf16x8 bf = *(const bf16x8*)(s_fc + sw256(frow, (unsigned)(ks * 32 + lh * 16)));
                acs = __builtin_amdgcn_mfma_f32_32x32x16_bf16(wf, bf, acs, 0, 0, 0);
            }
            if (l31 < BP) {             // cols 8..31 are garbage (unwritten fc rows) - unused
                const int p = l31;
                #pragma unroll
                for (int r = 0; r < 16; ++r) {
                    int e = dbase + (r & 3) + 8 * (r >> 2) + 4 * lh;
                    s_agg[p][e] += acs[r] + b2bs[r];
                }
            }
        }
        __syncthreads();

        // ================= LayerNorm: wave wv handles point wv =================
        {
            const int n = p0 + wv;
            float4 x = *(const float4*)&s_agg[wv][lane * 4];
            float s  = x.x + x.y + x.z + x.w;
            float ss = x.x*x.x + x.y*x.y + x.z*x.z + x.w*x.w;
            #pragma unroll
            for (int off = 1; off < 64; off <<= 1) {
                s  += __shfl_xor(s,  off);
                ss += __shfl_xor(ss, off);
            }
            const float mu   = s * (1.0f / 256.0f);
            const float var  = ss * (1.0f / 256.0f) - mu * mu;
            const float rstd = rsqrtf(var + 1e-5f);
            float4 g  = *(const float4*)&gamma[lane * 4];
            float4 be = *(const float4*)&beta[lane * 4];
            float4 o;
            o.x = (x.x - mu) * rstd * g.x + be.x;
            o.y = (x.y - mu) * rstd * g.y + be.y;
            o.z = (x.z - mu) * rstd * g.z + be.z;
            o.w = (x.w - mu) * rstd * g.w + be.w;
            *(float4*)&out[n * COUT + lane * 4] = o;
        }
        __syncthreads();   // protect LDS reuse next iteration
    }
}

extern "C" void kernel_launch(void* const* d_in, const int* in_sizes, int n_in,
                              void* d_out, int out_size, void* d_ws, size_t ws_size,
                              hipStream_t stream) {
    const float* feat  = (const float*)d_in[0];
    const int*   knn   = (const int*)  d_in[1];
    const float* W1    = (const float*)d_in[2];
    const float* b1    = (const float*)d_in[3];
    const float* W2    = (const float*)d_in[4];
    const float* b2    = (const float*)d_in[5];
    const float* Ws    = (const float*)d_in[6];
    const float* bs    = (const float*)d_in[7];
    const float* gamma = (const float*)d_in[8];
    const float* beta  = (const float*)d_in[9];
    float* out = (float*)d_out;

    unsigned short* w1t = (unsigned short*)d_ws;
    unsigned short* w2t = w1t + 65536;
    unsigned short* wst = w2t + 65536;   // total 320 KB of ws

    hipLaunchKernelGGL(prep_w, dim3(256), dim3(256), 0, stream, W1, W2, Ws, w1t, w2t, wst);
    hipLaunchKernelGGL(edgeconv_mfma, dim3(GRID), dim3(512), 0, stream,
                       feat, knn, w1t, w2t, wst, b1, b2, bs, gamma, beta, out);
}